// Round 11
// baseline (1086.381 us; speedup 1.0000x reference)
//
#include <hip/hip_runtime.h>
#include <math.h>
#include <stdint.h>

typedef unsigned short u16;
typedef __attribute__((ext_vector_type(8))) short short8;
typedef __attribute__((ext_vector_type(4))) float f32x4;

#define B_   4
#define S_   2048
#define D_   4096
#define H_   32
#define KVH_ 8
#define HD_  128
#define NQKV 6144
#define MTOT 8192
#define ATT_SCALE 0.08838834764831845f
#define SCL2 (ATT_SCALE * 1.4426950408889634f)   // scale * log2(e), for exp2
#define DEFER_THR 90.5f   // 8 / ATT_SCALE: P bounded by e^8, bf16-safe

__device__ __forceinline__ float bf2f(u16 u) {
  unsigned x = ((unsigned)u) << 16;
  return __builtin_bit_cast(float, x);
}
__device__ __forceinline__ u16 f2bf(float f) {
  unsigned x = __builtin_bit_cast(unsigned, f);
  x += 0x7fffu + ((x >> 16) & 1u);
  return (u16)(x >> 16);
}
// branch-free RNE pack (measured faster than __float22bfloat162_rn's header path)
__device__ __forceinline__ unsigned pack2bf(float a, float b) {
  return (unsigned)f2bf(a) | ((unsigned)f2bf(b) << 16);
}

// async global->LDS, 16B per lane. LDS dest = wave-uniform base + lane*16.
typedef const __attribute__((address_space(1))) void* gas1p;
typedef __attribute__((address_space(3))) void* las3p;
__device__ __forceinline__ void gload16(const void* g, void* l) {
  __builtin_amdgcn_global_load_lds((gas1p)g, (las3p)l, 16, 0, 0);
}

// swizzled element index for LDS tiles with 64-element (128B) rows, chunk=8 elems
__device__ __forceinline__ int swz64(int row, int kc) {
  return row * 64 + ((kc ^ (row & 7)) << 3);
}
// 128-element (256B) rows, kc 0..15
__device__ __forceinline__ int swz128(int row, int kc) {
  return row * 128 + ((kc ^ (row & 7)) << 3);
}

// ---------------- cast x (f32 -> bf16) ----------------
__global__ void cast_f32_to_bf16(const float* __restrict__ in, u16* __restrict__ out, long n) {
  long i = ((long)blockIdx.x * 256 + threadIdx.x) * 4;
  if (i >= n) return;
  float4 v = *(const float4*)(in + i);
  ushort4 o;
  o.x = f2bf(v.x); o.y = f2bf(v.y); o.z = f2bf(v.z); o.w = f2bf(v.w);
  *(ushort4*)(out + i) = o;
}

// ---------------- transpose+cast weight: f32 [K][N] -> bf16 [N][K] ----------------
__global__ void transpose_cast(const float* __restrict__ in, u16* __restrict__ out, int K, int N) {
  __shared__ u16 tile[32][33];
  int n0 = blockIdx.x * 32, k0 = blockIdx.y * 32;
  int tx = threadIdx.x, ty = threadIdx.y;
  for (int i = ty; i < 32; i += 8)
    tile[i][tx] = f2bf(in[(long)(k0 + i) * N + n0 + tx]);
  __syncthreads();
  for (int i = ty; i < 32; i += 8)
    out[(long)(n0 + i) * K + k0 + tx] = tile[tx][i];
}

// ---------------- 256x256 8-phase GEMM: C = A[M][K] * BT[N][K]^T -----------------
template <int OUTF32>
__global__ __launch_bounds__(512, 2) void gemm256(const u16* __restrict__ A,
                                                  const u16* __restrict__ BT,
                                                  void* __restrict__ Cout,
                                                  int M, int N, int K) {
  __shared__ u16 Ls[2][2][2][128 * 64];
  int tid = threadIdx.x, lane = tid & 63, wid = tid >> 6;
  int wm = wid >> 2, wn = wid & 3;
  int m0 = blockIdx.y * 256, n0 = blockIdx.x * 256;
  int frow = lane & 15, fk = lane >> 4;

  f32x4 acc[8][4];
#pragma unroll
  for (int i = 0; i < 8; i++)
#pragma unroll
    for (int j = 0; j < 4; j++) acc[i][j] = (f32x4){0.f, 0.f, 0.f, 0.f};

  // stage source (pre-swizzled col: involution key = row-within-half & 7 = lane>>3)
  int srow = lane >> 3;
  int sc = ((lane & 7) ^ srow) * 8;
  const u16* a0 = A + (long)(m0 + (2 * wid + 0) * 8 + srow) * K + sc;
  const u16* a1 = A + (long)(m0 + (2 * wid + 1) * 8 + srow) * K + sc;
  const u16* b0 = BT + (long)(n0 + (2 * wid + 0) * 8 + srow) * K + sc;
  const u16* b1 = BT + (long)(n0 + (2 * wid + 1) * 8 + srow) * K + sc;
  long hstep = (long)128 * K;

#define STAGE_A(buf, half, t) do {                                              \
    gload16(a0 + (half) * hstep + (long)(t) * 64, &Ls[buf][0][half][(2 * wid + 0) * 512]); \
    gload16(a1 + (half) * hstep + (long)(t) * 64, &Ls[buf][0][half][(2 * wid + 1) * 512]); \
  } while (0)
#define STAGE_B(buf, half, t) do {                                              \
    gload16(b0 + (half) * hstep + (long)(t) * 64, &Ls[buf][1][half][(2 * wid + 0) * 512]); \
    gload16(b1 + (half) * hstep + (long)(t) * 64, &Ls[buf][1][half][(2 * wid + 1) * 512]); \
  } while (0)

  int nk = K / 64;
  // prologue: tile0 (buf0) all 4 halves, then tile1 B halves -> vmcnt(4)
  STAGE_A(0, 0, 0); STAGE_A(0, 1, 0); STAGE_B(0, 0, 0); STAGE_B(0, 1, 0);
  STAGE_B(1, 0, 1); STAGE_B(1, 1, 1);
  asm volatile("s_waitcnt vmcnt(4)" ::: "memory");
  __builtin_amdgcn_s_barrier();

#define PHASE(P, STAGE_STMT, VM_STMT)                                           \
  {                                                                             \
    short8 af[2][2];                                                            \
    _Pragma("unroll") for (int mm = 0; mm < 2; mm++)                            \
      _Pragma("unroll") for (int kk = 0; kk < 2; kk++)                          \
        af[mm][kk] = *(const short8*)&Ah[swz64((2 * (P) + mm) * 16 + frow, kk * 4 + fk)]; \
    STAGE_STMT;                                                                 \
    VM_STMT;                                                                    \
    __builtin_amdgcn_s_barrier();                                               \
    asm volatile("s_waitcnt lgkmcnt(0)" ::: "memory");                          \
    __builtin_amdgcn_sched_barrier(0);                                          \
    __builtin_amdgcn_s_setprio(1);                                              \
    _Pragma("unroll") for (int mm = 0; mm < 2; mm++)                            \
      _Pragma("unroll") for (int n = 0; n < 4; n++)                             \
        _Pragma("unroll") for (int kk = 0; kk < 2; kk++)                        \
          acc[2 * (P) + mm][n] = __builtin_amdgcn_mfma_f32_16x16x32_bf16(       \
              af[mm][kk], bfr[n][kk], acc[2 * (P) + mm][n], 0, 0, 0);           \
    __builtin_amdgcn_s_setprio(0);                                              \
    __builtin_amdgcn_s_barrier();                                               \
  }

  for (int t = 0; t < nk; ++t) {
    int pi = t & 1;
    const u16* Ah = &Ls[pi][0][wm][0];
    const u16* Bh = &Ls[pi][1][wn >> 1][0];
    int brow = (wn & 1) * 64;
    short8 bfr[4][2];
#pragma unroll
    for (int n = 0; n < 4; n++)
#pragma unroll
      for (int kk = 0; kk < 2; kk++)
        bfr[n][kk] = *(const short8*)&Bh[swz64(brow + n * 16 + frow, kk * 4 + fk)];

    PHASE(0, if (t + 1 < nk) STAGE_A(pi ^ 1, 0, t + 1), );
    PHASE(1, if (t + 1 < nk) STAGE_A(pi ^ 1, 1, t + 1), );
    PHASE(2, if (t + 2 < nk) STAGE_B(pi, 0, t + 2), );
    PHASE(3, if (t + 2 < nk) STAGE_B(pi, 1, t + 2),
          if (t + 2 < nk) { asm volatile("s_waitcnt vmcnt(4)" ::: "memory"); }
          else            { asm volatile("s_waitcnt vmcnt(0)" ::: "memory"); });
  }
#undef PHASE
#undef STAGE_A
#undef STAGE_B

  // epilogue: C/D layout col=lane&15 (from B), row=fk*4+reg (from A)
  int cc = lane & 15, cr = fk * 4;
#pragma unroll
  for (int i = 0; i < 8; i++)
#pragma unroll
    for (int j = 0; j < 4; j++)
#pragma unroll
      for (int r = 0; r < 4; r++) {
        int m = m0 + wm * 128 + i * 16 + cr + r;
        int n = n0 + wn * 64 + j * 16 + cc;
        if (OUTF32)
          ((float*)Cout)[(long)m * N + n] = acc[i][j][r];
        else
          ((u16*)Cout)[(long)m * N + n] = f2bf(acc[i][j][r]);
      }
}

// ---------------- RoPE in-place on qkv buffer: K columns only -------------------
// (Q RoPE is fused into attn_kernel's Q fragment load)
__global__ void rope_k_kernel(u16* __restrict__ qkv, const float* __restrict__ cosb,
                              const float* __restrict__ sinb, const int* __restrict__ start_pos) {
  long tid = (long)blockIdx.x * 256 + threadIdx.x;
  const long total = (long)MTOT * 512;  // 512 K pairs per row
  if (tid >= total) return;
  int row = (int)(tid >> 9);
  int p = (int)(tid & 511);
  int col = D_ + p * 2;
  int i = p & 63;
  int s = row & (S_ - 1);
  int pos = s + *start_pos;
  float c = cosb[pos * 64 + i];
  float sn = sinb[pos * 64 + i];
  u16* ptr = qkv + (long)row * NQKV + col;
  unsigned v = *(unsigned*)ptr;
  float x0 = bf2f((u16)(v & 0xffff));
  float x1 = bf2f((u16)(v >> 16));
  float o0 = x0 * c - x1 * sn;
  float o1 = x0 * sn + x1 * c;
  *(unsigned*)ptr = pack2bf(o0, o1);
}

// ---------------- build VT[b][kvh][d=128][s=2048] from qkv V columns ----------------
__global__ void build_vt(const u16* __restrict__ qkv, u16* __restrict__ vt) {
  int bk = blockIdx.z;
  int b = bk >> 3, kvh = bk & 7;
  int s0 = blockIdx.x * 32, d0 = blockIdx.y * 32;
  __shared__ u16 tile[32][33];
  int tx = threadIdx.x, ty = threadIdx.y;
  const u16* src = qkv + (long)(b * S_) * NQKV + D_ + KVH_ * HD_ + kvh * HD_;
  for (int i = ty; i < 32; i += 8)
    tile[i][tx] = src[(long)(s0 + i) * NQKV + d0 + tx];
  __syncthreads();
  u16* dst = vt + ((long)(b * KVH_ + kvh) * HD_) * S_;
  for (int i = ty; i < 32; i += 8)
    dst[(long)(d0 + i) * S_ + s0 + tx] = tile[tx][i];
}

// ---------------- flash attention (non-causal, GQA), swapped-operand form -------
// 128 q/block (4 waves x 32 q). K/V LDS double-buffered, counted vmcnt(8).
// Q-RoPE fused at fragment load. Softmax: exp2 with folded log2e, tree max,
// branch-free pack2bf, defer-max rescale (THR=8).
__global__ __launch_bounds__(256, 2) void attn_kernel(const u16* __restrict__ qkv,
                                                      const u16* __restrict__ vt,
                                                      u16* __restrict__ obuf,
                                                      const float* __restrict__ cosb,
                                                      const float* __restrict__ sinb,
                                                      const int* __restrict__ start_pos) {
  int nb = gridDim.x;
  int fid = (int)((blockIdx.x & 7) * (nb >> 3) + (blockIdx.x >> 3));
  int bx = fid & 15;
  int bh = fid >> 4;
  int b = bh >> 5, h = bh & 31;
  int kvh = h >> 2;
  int q0 = bx * 128;
  int tid = threadIdx.x, lane = tid & 63, wid = tid >> 6;

  __shared__ u16 Ks[2][64 * 128];
  __shared__ u16 VTs[2][128 * 64];
  __shared__ u16 Ps[4][32 * 64];

  int frow = lane & 15;
  int fk = lane >> 4;

  // Q fragments with fused RoPE: 8 elems at d = kd*32 + fk*8 + 0..7 = 4 aligned pairs
  short8 qf[2][4];
#pragma unroll
  for (int qq = 0; qq < 2; ++qq) {
    int s = q0 + wid * 32 + qq * 16 + frow;
    int pos = s + *start_pos;
    const float* cb = cosb + pos * 64;
    const float* sb = sinb + pos * 64;
    const u16* qbase = qkv + (long)(b * S_ + s) * NQKV + h * HD_;
#pragma unroll
    for (int kd = 0; kd < 4; ++kd) {
      short8 v = *(const short8*)(qbase + kd * 32 + fk * 8);
      union { short8 s8; unsigned u[4]; } w;
#pragma unroll
      for (int j = 0; j < 4; ++j) {
        int i = kd * 16 + fk * 4 + j;
        float c = cb[i], sn = sb[i];
        float x0 = bf2f((u16)v[2 * j]), x1 = bf2f((u16)v[2 * j + 1]);
        w.u[j] = pack2bf(x0 * c - x1 * sn, x0 * sn + x1 * c);
      }
      qf[qq][kd] = w.s8;
    }
  }

  f32x4 acc_o[2][8];
#pragma unroll
  for (int qq = 0; qq < 2; qq++)
#pragma unroll
    for (int i = 0; i < 8; i++) acc_o[qq][i] = (f32x4){0.f, 0.f, 0.f, 0.f};
  float m_r[2] = {-1e30f, -1e30f};
  float l_r[2] = {0.f, 0.f};

  const u16* kgl[4];
  const u16* vgl[4];
#pragma unroll
  for (int j = 0; j < 4; j++) {
    int gk = j * 4 + wid;
    int rk = gk * 4 + (lane >> 4);
    int ck = (lane & 15) ^ (rk & 7);
    kgl[j] = qkv + (long)(b * S_ + rk) * NQKV + D_ + kvh * HD_ + ck * 8;
    int gv = j * 4 + wid;
    int rv = gv * 8 + (lane >> 3);
    int cv = (lane & 7) ^ (rv & 7);
    vgl[j] = vt + ((long)(b * KVH_ + kvh) * HD_ + rv) * S_ + cv * 8;
  }

#define STAGE_KV(buf, t) do {                                                   \
    _Pragma("unroll") for (int j = 0; j < 4; j++) {                             \
      int g = j * 4 + wid;                                                      \
      gload16(kgl[j] + (long)((t) * 64) * NQKV, &Ks[buf][g * 512]);             \
      gload16(vgl[j] + (t) * 64, &VTs[buf][g * 512]);                           \
    }                                                                           \
  } while (0)

  const int ntiles = S_ / 64;
  STAGE_KV(0, 0);

  for (int t = 0; t < ntiles; ++t) {
    if (t + 1 < ntiles) {
      STAGE_KV((t + 1) & 1, t + 1);
      asm volatile("s_waitcnt vmcnt(8)" ::: "memory");  // tile t's 8 done; t+1 in flight
    } else {
      asm volatile("s_waitcnt vmcnt(0)" ::: "memory");
    }
    __builtin_amdgcn_s_barrier();   // raw: do NOT drain the in-flight prefetch
    __builtin_amdgcn_sched_barrier(0);
    const u16* Kb = &Ks[t & 1][0];
    const u16* Vb = &VTs[t & 1][0];

    // QK^T swapped: lane holds q=frow, kv = f*16 + 4*fk + r
    f32x4 sc[4][2];
#pragma unroll
    for (int f = 0; f < 4; f++)
#pragma unroll
      for (int qq = 0; qq < 2; qq++) sc[f][qq] = (f32x4){0.f, 0.f, 0.f, 0.f};
#pragma unroll
    for (int f = 0; f < 4; f++)
#pragma unroll
      for (int kd = 0; kd < 4; kd++) {
        short8 kf = *(const short8*)&Kb[swz128(f * 16 + frow, kd * 4 + fk)];
        sc[f][0] = __builtin_amdgcn_mfma_f32_16x16x32_bf16(kf, qf[0][kd], sc[f][0], 0, 0, 0);
        sc[f][1] = __builtin_amdgcn_mfma_f32_16x16x32_bf16(kf, qf[1][kd], sc[f][1], 0, 0, 0);
      }

    // tile max per qq: tree reduce (lane-local) + 2 shfl
    float mx[2];
#pragma unroll
    for (int qq = 0; qq < 2; ++qq) {
      float mf[4];
#pragma unroll
      for (int f = 0; f < 4; f++)
        mf[f] = fmaxf(fmaxf(sc[f][qq][0], sc[f][qq][1]), fmaxf(sc[f][qq][2], sc[f][qq][3]));
      float m = fmaxf(fmaxf(mf[0], mf[1]), fmaxf(mf[2], mf[3]));
      m = fmaxf(m, __shfl_xor(m, 16, 64));
      m = fmaxf(m, __shfl_xor(m, 32, 64));
      mx[qq] = m;
    }
    // defer-max: rescale only if some row's max grew past THR
    if (!__all((mx[0] <= m_r[0] + DEFER_THR) && (mx[1] <= m_r[1] + DEFER_THR))) {
#pragma unroll
      for (int qq = 0; qq < 2; ++qq) {
        float mnew = fmaxf(m_r[qq], mx[qq]);
        float scl = exp2f((m_r[qq] - mnew) * SCL2);
        l_r[qq] *= scl;
        m_r[qq] = mnew;
#pragma unroll
        for (int df = 0; df < 8; df++) acc_o[qq][df] *= scl;
      }
    }

    // P = exp2((s - m)*scl2), bf16-pack to LDS; row-sum into l
#pragma unroll
    for (int qq = 0; qq < 2; ++qq) {
      float nms = -m_r[qq] * SCL2;
      float rs = 0.f;
      int prow = qq * 16 + frow;
      int pbase = prow * 64 + (fk & 1) * 4;
      int q7 = frow & 7;
#pragma unroll
      for (int f = 0; f < 4; f++) {
        float p0 = exp2f(fmaf(sc[f][qq][0], SCL2, nms));
        float p1 = exp2f(fmaf(sc[f][qq][1], SCL2, nms));
        float p2 = exp2f(fmaf(sc[f][qq][2], SCL2, nms));
        float p3 = exp2f(fmaf(sc[f][qq][3], SCL2, nms));
        rs += (p0 + p1) + (p2 + p3);
        int chunk = (f * 2 + (fk >> 1)) ^ q7;
        uint2 wv2; wv2.x = pack2bf(p0, p1); wv2.y = pack2bf(p2, p3);
        *(uint2*)&Ps[wid][pbase + (chunk << 3)] = wv2;
      }
      rs += __shfl_xor(rs, 16, 64);
      rs += __shfl_xor(rs, 32, 64);
      l_r[qq] += rs;
    }

    asm volatile("s_waitcnt lgkmcnt(0)" ::: "memory");
    __builtin_amdgcn_sched_barrier(0);

    // PV swapped: O^T += VT * P^T
    short8 pf[2][2];
#pragma unroll
    for (int qq = 0; qq < 2; qq++)
#pragma unroll
      for (int kk = 0; kk < 2; kk++)
        pf[qq][kk] = *(const short8*)&Ps[wid][(qq * 16 + frow) * 64 + (((kk * 4 + fk) ^ (frow & 7)) << 3)];
#pragma unroll
    for (int df = 0; df < 8; df++)
#pragma unroll
      for (int kk = 0; kk < 2; kk++) {
        short8 vf = *(const short8*)&Vb[swz64(df * 16 + frow, kk * 4 + fk)];
        acc_o[0][df] = __builtin_amdgcn_mfma_f32_16x16x32_bf16(vf, pf[0][kk], acc_o[0][df], 0, 0, 0);
        acc_o[1][df] = __builtin_amdgcn_mfma_f32_16x16x32_bf16(vf, pf[1][kk], acc_o[1][df], 0, 0, 0);
      }
    __syncthreads();  // drain + barrier: all reads done before next-iter stage overwrites
  }
#undef STAGE_KV

#pragma unroll
  for (int qq = 0; qq < 2; ++qq) {
    float inv = 1.0f / l_r[qq];
    long srow = (long)(b * S_ + q0 + wid * 32 + qq * 16 + frow);
    u16* orow = obuf + srow * D_ + h * HD_ + fk * 4;
#pragma unroll
    for (int df = 0; df < 8; df++) {
      uint2 ov;
      ov.x = pack2bf(acc_o[qq][df][0] * inv, acc_o[qq][df][1] * inv);
      ov.y = pack2bf(acc_o[qq][df][2] * inv, acc_o[qq][df][3] * inv);
      *(uint2*)(orow + df * 16) = ov;
    }
  }
}

// ---------------- launch ----------------
extern "C" void kernel_launch(void* const* d_in, const int* in_sizes, int n_in,
                              void* d_out, int out_size, void* d_ws, size_t ws_size,
                              hipStream_t stream) {
  const float* x = (const float*)d_in[0];
  const float* wq = (const float*)d_in[1];
  const float* wk = (const float*)d_in[2];
  const float* wv = (const float*)d_in[3];
  const float* wo = (const float*)d_in[4];
  const float* cosb = (const float*)d_in[5];
  const float* sinb = (const float*)d_in[6];
  const int* start_pos = (const int*)d_in[9];
  float* out = (float*)d_out;

  char* ws = (char*)d_ws;
  u16* xb = (u16*)ws;                                   // [8192][4096] bf16: 67108864 B
  u16* wqkvT = (u16*)(ws + 67108864L);                  // [6144][4096] bf16: 50331648 B
  u16* woT = (u16*)(ws + 117440512L);                   // [4096][4096] bf16: 33554432 B
  u16* qkvb = (u16*)(ws + 150994944L);                  // [8192][6144] bf16: 100663296 B
  u16* vtb = (u16*)(ws + 251658240L);                   // [4][8][128][2048] bf16: 16777216 B
  u16* obuf = xb;                                       // reuse xb after GEMM1

  // 1. cast x
  cast_f32_to_bf16<<<dim3(32768), dim3(256), 0, stream>>>(x, xb, (long)MTOT * D_);

  // 2. transpose-cast weights into B^T layout
  transpose_cast<<<dim3(128, 128), dim3(32, 8), 0, stream>>>(wq, wqkvT, D_, 4096);
  transpose_cast<<<dim3(32, 128), dim3(32, 8), 0, stream>>>(wk, wqkvT + (long)4096 * D_, D_, 1024);
  transpose_cast<<<dim3(32, 128), dim3(32, 8), 0, stream>>>(wv, wqkvT + (long)5120 * D_, D_, 1024);
  transpose_cast<<<dim3(128, 128), dim3(32, 8), 0, stream>>>(wo, woT, D_, 4096);

  // 3. QKV GEMM: [8192][6144] = xb * wqkvT^T  (256^2 8-phase)
  gemm256<0><<<dim3(NQKV / 256, MTOT / 256), dim3(512), 0, stream>>>(xb, wqkvT, qkvb, MTOT, NQKV, D_);

  // 4. RoPE in-place on K columns only (Q fused into attn)
  rope_k_kernel<<<dim3(16384), dim3(256), 0, stream>>>(qkvb, cosb, sinb, start_pos);

  // 5. V transpose
  build_vt<<<dim3(64, 4, 32), dim3(32, 8), 0, stream>>>(qkvb, vtb);

  // 6. attention: flat grid 16 x 128 = 2048
  attn_kernel<<<dim3(2048), dim3(256), 0, stream>>>(qkvb, vtb, obuf, cosb, sinb, start_pos);

  // 7. output GEMM: out f32 = obuf * woT^T  (256^2 8-phase)
  gemm256<1><<<dim3(D_ / 256, MTOT / 256), dim3(512), 0, stream>>>(obuf, woT, out, MTOT, D_, D_);
}

// Round 12
// 1040.671 us; speedup vs baseline: 1.0439x; 1.0439x over previous
//
#include <hip/hip_runtime.h>
#include <math.h>
#include <stdint.h>

typedef unsigned short u16;
typedef __attribute__((ext_vector_type(8))) short short8;
typedef __attribute__((ext_vector_type(4))) float f32x4;

#define B_   4
#define S_   2048
#define D_   4096
#define H_   32
#define KVH_ 8
#define HD_  128
#define NQKV 6144
#define MTOT 8192
#define ATT_SCALE 0.08838834764831845f
#define DEFER_THR 90.5f   // 8 / ATT_SCALE: P bounded by e^8, bf16-safe

__device__ __forceinline__ float bf2f(u16 u) {
  unsigned x = ((unsigned)u) << 16;
  return __builtin_bit_cast(float, x);
}
__device__ __forceinline__ u16 f2bf(float f) {
  unsigned x = __builtin_bit_cast(unsigned, f);
  x += 0x7fffu + ((x >> 16) & 1u);
  return (u16)(x >> 16);
}
// branch-free RNE pack
__device__ __forceinline__ unsigned pack2bf(float a, float b) {
  return (unsigned)f2bf(a) | ((unsigned)f2bf(b) << 16);
}

// async global->LDS, 16B per lane. LDS dest = wave-uniform base + lane*16.
typedef const __attribute__((address_space(1))) void* gas1p;
typedef __attribute__((address_space(3))) void* las3p;
__device__ __forceinline__ void gload16(const void* g, void* l) {
  __builtin_amdgcn_global_load_lds((gas1p)g, (las3p)l, 16, 0, 0);
}

// swizzled element index for LDS tiles with 64-element (128B) rows, chunk=8 elems
__device__ __forceinline__ int swz64(int row, int kc) {
  return row * 64 + ((kc ^ (row & 7)) << 3);
}
// 128-element (256B) rows, kc 0..15
__device__ __forceinline__ int swz128(int row, int kc) {
  return row * 128 + ((kc ^ (row & 7)) << 3);
}

// ---------------- cast x (f32 -> bf16) ----------------
__global__ void cast_f32_to_bf16(const float* __restrict__ in, u16* __restrict__ out, long n) {
  long i = ((long)blockIdx.x * 256 + threadIdx.x) * 4;
  if (i >= n) return;
  float4 v = *(const float4*)(in + i);
  ushort4 o;
  o.x = f2bf(v.x); o.y = f2bf(v.y); o.z = f2bf(v.z); o.w = f2bf(v.w);
  *(ushort4*)(out + i) = o;
}

// ---------------- transpose+cast weight: f32 [K][N] -> bf16 [N][K] ----------------
__global__ void transpose_cast(const float* __restrict__ in, u16* __restrict__ out, int K, int N) {
  __shared__ u16 tile[32][33];
  int n0 = blockIdx.x * 32, k0 = blockIdx.y * 32;
  int tx = threadIdx.x, ty = threadIdx.y;
  for (int i = ty; i < 32; i += 8)
    tile[i][tx] = f2bf(in[(long)(k0 + i) * N + n0 + tx]);
  __syncthreads();
  for (int i = ty; i < 32; i += 8)
    out[(long)(n0 + i) * K + k0 + tx] = tile[tx][i];
}

// ---------------- 256x256 8-phase GEMM: C = A[M][K] * BT[N][K]^T -----------------
template <int OUTF32>
__global__ __launch_bounds__(512, 2) void gemm256(const u16* __restrict__ A,
                                                  const u16* __restrict__ BT,
                                                  void* __restrict__ Cout,
                                                  int M, int N, int K) {
  __shared__ u16 Ls[2][2][2][128 * 64];
  int tid = threadIdx.x, lane = tid & 63, wid = tid >> 6;
  int wm = wid >> 2, wn = wid & 3;
  int m0 = blockIdx.y * 256, n0 = blockIdx.x * 256;
  int frow = lane & 15, fk = lane >> 4;

  f32x4 acc[8][4];
#pragma unroll
  for (int i = 0; i < 8; i++)
#pragma unroll
    for (int j = 0; j < 4; j++) acc[i][j] = (f32x4){0.f, 0.f, 0.f, 0.f};

  // stage source (pre-swizzled col: involution key = row-within-half & 7 = lane>>3)
  int srow = lane >> 3;
  int sc = ((lane & 7) ^ srow) * 8;
  const u16* a0 = A + (long)(m0 + (2 * wid + 0) * 8 + srow) * K + sc;
  const u16* a1 = A + (long)(m0 + (2 * wid + 1) * 8 + srow) * K + sc;
  const u16* b0 = BT + (long)(n0 + (2 * wid + 0) * 8 + srow) * K + sc;
  const u16* b1 = BT + (long)(n0 + (2 * wid + 1) * 8 + srow) * K + sc;
  long hstep = (long)128 * K;

#define STAGE_A(buf, half, t) do {                                              \
    gload16(a0 + (half) * hstep + (long)(t) * 64, &Ls[buf][0][half][(2 * wid + 0) * 512]); \
    gload16(a1 + (half) * hstep + (long)(t) * 64, &Ls[buf][0][half][(2 * wid + 1) * 512]); \
  } while (0)
#define STAGE_B(buf, half, t) do {                                              \
    gload16(b0 + (half) * hstep + (long)(t) * 64, &Ls[buf][1][half][(2 * wid + 0) * 512]); \
    gload16(b1 + (half) * hstep + (long)(t) * 64, &Ls[buf][1][half][(2 * wid + 1) * 512]); \
  } while (0)

  int nk = K / 64;
  // prologue: tile0 (buf0) all 4 halves, then tile1 B halves -> vmcnt(4)
  STAGE_A(0, 0, 0); STAGE_A(0, 1, 0); STAGE_B(0, 0, 0); STAGE_B(0, 1, 0);
  STAGE_B(1, 0, 1); STAGE_B(1, 1, 1);
  asm volatile("s_waitcnt vmcnt(4)" ::: "memory");
  __builtin_amdgcn_s_barrier();

#define PHASE(P, STAGE_STMT, VM_STMT)                                           \
  {                                                                             \
    short8 af[2][2];                                                            \
    _Pragma("unroll") for (int mm = 0; mm < 2; mm++)                            \
      _Pragma("unroll") for (int kk = 0; kk < 2; kk++)                          \
        af[mm][kk] = *(const short8*)&Ah[swz64((2 * (P) + mm) * 16 + frow, kk * 4 + fk)]; \
    STAGE_STMT;                                                                 \
    VM_STMT;                                                                    \
    __builtin_amdgcn_s_barrier();                                               \
    asm volatile("s_waitcnt lgkmcnt(0)" ::: "memory");                          \
    __builtin_amdgcn_sched_barrier(0);                                          \
    __builtin_amdgcn_s_setprio(1);                                              \
    _Pragma("unroll") for (int mm = 0; mm < 2; mm++)                            \
      _Pragma("unroll") for (int n = 0; n < 4; n++)                             \
        _Pragma("unroll") for (int kk = 0; kk < 2; kk++)                        \
          acc[2 * (P) + mm][n] = __builtin_amdgcn_mfma_f32_16x16x32_bf16(       \
              af[mm][kk], bfr[n][kk], acc[2 * (P) + mm][n], 0, 0, 0);           \
    __builtin_amdgcn_s_setprio(0);                                              \
    __builtin_amdgcn_s_barrier();                                               \
  }

  for (int t = 0; t < nk; ++t) {
    int pi = t & 1;
    const u16* Ah = &Ls[pi][0][wm][0];
    const u16* Bh = &Ls[pi][1][wn >> 1][0];
    int brow = (wn & 1) * 64;
    short8 bfr[4][2];
#pragma unroll
    for (int n = 0; n < 4; n++)
#pragma unroll
      for (int kk = 0; kk < 2; kk++)
        bfr[n][kk] = *(const short8*)&Bh[swz64(brow + n * 16 + frow, kk * 4 + fk)];

    PHASE(0, if (t + 1 < nk) STAGE_A(pi ^ 1, 0, t + 1), );
    PHASE(1, if (t + 1 < nk) STAGE_A(pi ^ 1, 1, t + 1), );
    PHASE(2, if (t + 2 < nk) STAGE_B(pi, 0, t + 2), );
    PHASE(3, if (t + 2 < nk) STAGE_B(pi, 1, t + 2),
          if (t + 2 < nk) { asm volatile("s_waitcnt vmcnt(4)" ::: "memory"); }
          else            { asm volatile("s_waitcnt vmcnt(0)" ::: "memory"); });
  }
#undef PHASE
#undef STAGE_A
#undef STAGE_B

  // epilogue: C/D layout col=lane&15 (from B), row=fk*4+reg (from A)
  int cc = lane & 15, cr = fk * 4;
#pragma unroll
  for (int i = 0; i < 8; i++)
#pragma unroll
    for (int j = 0; j < 4; j++)
#pragma unroll
      for (int r = 0; r < 4; r++) {
        int m = m0 + wm * 128 + i * 16 + cr + r;
        int n = n0 + wn * 64 + j * 16 + cc;
        if (OUTF32)
          ((float*)Cout)[(long)m * N + n] = acc[i][j][r];
        else
          ((u16*)Cout)[(long)m * N + n] = f2bf(acc[i][j][r]);
      }
}

// ---------------- RoPE in-place on qkv buffer: K columns only -------------------
__global__ void rope_k_kernel(u16* __restrict__ qkv, const float* __restrict__ cosb,
                              const float* __restrict__ sinb, const int* __restrict__ start_pos) {
  long tid = (long)blockIdx.x * 256 + threadIdx.x;
  const long total = (long)MTOT * 512;  // 512 K pairs per row
  if (tid >= total) return;
  int row = (int)(tid >> 9);
  int p = (int)(tid & 511);
  int col = D_ + p * 2;
  int i = p & 63;
  int s = row & (S_ - 1);
  int pos = s + *start_pos;
  float c = cosb[pos * 64 + i];
  float sn = sinb[pos * 64 + i];
  u16* ptr = qkv + (long)row * NQKV + col;
  unsigned v = *(unsigned*)ptr;
  float x0 = bf2f((u16)(v & 0xffff));
  float x1 = bf2f((u16)(v >> 16));
  float o0 = x0 * c - x1 * sn;
  float o1 = x0 * sn + x1 * c;
  *(unsigned*)ptr = pack2bf(o0, o1);
}

// ---------------- build VT[b][kvh][d=128][s=2048] from qkv V columns ----------------
__global__ void build_vt(const u16* __restrict__ qkv, u16* __restrict__ vt) {
  int bk = blockIdx.z;
  int b = bk >> 3, kvh = bk & 7;
  int s0 = blockIdx.x * 32, d0 = blockIdx.y * 32;
  __shared__ u16 tile[32][33];
  int tx = threadIdx.x, ty = threadIdx.y;
  const u16* src = qkv + (long)(b * S_) * NQKV + D_ + KVH_ * HD_ + kvh * HD_;
  for (int i = ty; i < 32; i += 8)
    tile[i][tx] = src[(long)(s0 + i) * NQKV + d0 + tx];
  __syncthreads();
  u16* dst = vt + ((long)(b * KVH_ + kvh) * HD_) * S_;
  for (int i = ty; i < 32; i += 8)
    dst[(long)(d0 + i) * S_ + s0 + tx] = tile[tx][i];
}

// ---------------- flash attention (non-causal, GQA), swapped-operand form -------
// 128 q/block (4 waves x 32 q). K/V LDS double-buffered, counted vmcnt(8).
// Q-RoPE fused at fragment load. Softmax: __expf (native), tree max, pack2bf,
// defer-max rescale (THR=8).
__global__ __launch_bounds__(256, 2) void attn_kernel(const u16* __restrict__ qkv,
                                                      const u16* __restrict__ vt,
                                                      u16* __restrict__ obuf,
                                                      const float* __restrict__ cosb,
                                                      const float* __restrict__ sinb,
                                                      const int* __restrict__ start_pos) {
  int nb = gridDim.x;
  int fid = (int)((blockIdx.x & 7) * (nb >> 3) + (blockIdx.x >> 3));
  int bx = fid & 15;
  int bh = fid >> 4;
  int b = bh >> 5, h = bh & 31;
  int kvh = h >> 2;
  int q0 = bx * 128;
  int tid = threadIdx.x, lane = tid & 63, wid = tid >> 6;

  __shared__ u16 Ks[2][64 * 128];
  __shared__ u16 VTs[2][128 * 64];
  __shared__ u16 Ps[4][32 * 64];

  int frow = lane & 15;
  int fk = lane >> 4;

  // Q fragments with fused RoPE: 8 elems at d = kd*32 + fk*8 + 0..7 = 4 aligned pairs
  short8 qf[2][4];
#pragma unroll
  for (int qq = 0; qq < 2; ++qq) {
    int s = q0 + wid * 32 + qq * 16 + frow;
    int pos = s + *start_pos;
    const float* cb = cosb + pos * 64;
    const float* sb = sinb + pos * 64;
    const u16* qbase = qkv + (long)(b * S_ + s) * NQKV + h * HD_;
#pragma unroll
    for (int kd = 0; kd < 4; ++kd) {
      short8 v = *(const short8*)(qbase + kd * 32 + fk * 8);
      union { short8 s8; unsigned u[4]; } w;
#pragma unroll
      for (int j = 0; j < 4; ++j) {
        int i = kd * 16 + fk * 4 + j;
        float c = cb[i], sn = sb[i];
        float x0 = bf2f((u16)v[2 * j]), x1 = bf2f((u16)v[2 * j + 1]);
        w.u[j] = pack2bf(x0 * c - x1 * sn, x0 * sn + x1 * c);
      }
      qf[qq][kd] = w.s8;
    }
  }

  f32x4 acc_o[2][8];
#pragma unroll
  for (int qq = 0; qq < 2; qq++)
#pragma unroll
    for (int i = 0; i < 8; i++) acc_o[qq][i] = (f32x4){0.f, 0.f, 0.f, 0.f};
  float m_r[2] = {-1e30f, -1e30f};
  float l_r[2] = {0.f, 0.f};

  const u16* kgl[4];
  const u16* vgl[4];
#pragma unroll
  for (int j = 0; j < 4; j++) {
    int gk = j * 4 + wid;
    int rk = gk * 4 + (lane >> 4);
    int ck = (lane & 15) ^ (rk & 7);
    kgl[j] = qkv + (long)(b * S_ + rk) * NQKV + D_ + kvh * HD_ + ck * 8;
    int gv = j * 4 + wid;
    int rv = gv * 8 + (lane >> 3);
    int cv = (lane & 7) ^ (rv & 7);
    vgl[j] = vt + ((long)(b * KVH_ + kvh) * HD_ + rv) * S_ + cv * 8;
  }

#define STAGE_KV(buf, t) do {                                                   \
    _Pragma("unroll") for (int j = 0; j < 4; j++) {                             \
      int g = j * 4 + wid;                                                      \
      gload16(kgl[j] + (long)((t) * 64) * NQKV, &Ks[buf][g * 512]);             \
      gload16(vgl[j] + (t) * 64, &VTs[buf][g * 512]);                           \
    }                                                                           \
  } while (0)

  const int ntiles = S_ / 64;
  STAGE_KV(0, 0);

  for (int t = 0; t < ntiles; ++t) {
    if (t + 1 < ntiles) {
      STAGE_KV((t + 1) & 1, t + 1);
      asm volatile("s_waitcnt vmcnt(8)" ::: "memory");  // tile t's 8 done; t+1 in flight
    } else {
      asm volatile("s_waitcnt vmcnt(0)" ::: "memory");
    }
    __builtin_amdgcn_s_barrier();   // raw: do NOT drain the in-flight prefetch
    __builtin_amdgcn_sched_barrier(0);
    const u16* Kb = &Ks[t & 1][0];
    const u16* Vb = &VTs[t & 1][0];

    // QK^T swapped: lane holds q=frow, kv = f*16 + 4*fk + r
    f32x4 sc[4][2];
#pragma unroll
    for (int f = 0; f < 4; f++)
#pragma unroll
      for (int qq = 0; qq < 2; qq++) sc[f][qq] = (f32x4){0.f, 0.f, 0.f, 0.f};
#pragma unroll
    for (int f = 0; f < 4; f++)
#pragma unroll
      for (int kd = 0; kd < 4; kd++) {
        short8 kf = *(const short8*)&Kb[swz128(f * 16 + frow, kd * 4 + fk)];
        sc[f][0] = __builtin_amdgcn_mfma_f32_16x16x32_bf16(kf, qf[0][kd], sc[f][0], 0, 0, 0);
        sc[f][1] = __builtin_amdgcn_mfma_f32_16x16x32_bf16(kf, qf[1][kd], sc[f][1], 0, 0, 0);
      }

    // tile max per qq: tree reduce (lane-local) + 2 shfl
    float mx[2];
#pragma unroll
    for (int qq = 0; qq < 2; ++qq) {
      float mf[4];
#pragma unroll
      for (int f = 0; f < 4; f++)
        mf[f] = fmaxf(fmaxf(sc[f][qq][0], sc[f][qq][1]), fmaxf(sc[f][qq][2], sc[f][qq][3]));
      float m = fmaxf(fmaxf(mf[0], mf[1]), fmaxf(mf[2], mf[3]));
      m = fmaxf(m, __shfl_xor(m, 16, 64));
      m = fmaxf(m, __shfl_xor(m, 32, 64));
      mx[qq] = m;
    }
    // defer-max: rescale only if some row's max grew past THR
    if (!__all((mx[0] <= m_r[0] + DEFER_THR) && (mx[1] <= m_r[1] + DEFER_THR))) {
#pragma unroll
      for (int qq = 0; qq < 2; ++qq) {
        float mnew = fmaxf(m_r[qq], mx[qq]);
        float scl = __expf((m_r[qq] - mnew) * ATT_SCALE);
        l_r[qq] *= scl;
        m_r[qq] = mnew;
#pragma unroll
        for (int df = 0; df < 8; df++) acc_o[qq][df] *= scl;
      }
    }

    // P = __expf((s - m)*scale), bf16-pack to LDS; row-sum into l
#pragma unroll
    for (int qq = 0; qq < 2; ++qq) {
      float nms = -m_r[qq] * ATT_SCALE;
      float rs = 0.f;
      int prow = qq * 16 + frow;
      int pbase = prow * 64 + (fk & 1) * 4;
      int q7 = frow & 7;
#pragma unroll
      for (int f = 0; f < 4; f++) {
        float p0 = __expf(fmaf(sc[f][qq][0], ATT_SCALE, nms));
        float p1 = __expf(fmaf(sc[f][qq][1], ATT_SCALE, nms));
        float p2 = __expf(fmaf(sc[f][qq][2], ATT_SCALE, nms));
        float p3 = __expf(fmaf(sc[f][qq][3], ATT_SCALE, nms));
        rs += (p0 + p1) + (p2 + p3);
        int chunk = (f * 2 + (fk >> 1)) ^ q7;
        uint2 wv2; wv2.x = pack2bf(p0, p1); wv2.y = pack2bf(p2, p3);
        *(uint2*)&Ps[wid][pbase + (chunk << 3)] = wv2;
      }
      rs += __shfl_xor(rs, 16, 64);
      rs += __shfl_xor(rs, 32, 64);
      l_r[qq] += rs;
    }

    asm volatile("s_waitcnt lgkmcnt(0)" ::: "memory");
    __builtin_amdgcn_sched_barrier(0);

    // PV swapped: O^T += VT * P^T
    short8 pf[2][2];
#pragma unroll
    for (int qq = 0; qq < 2; qq++)
#pragma unroll
      for (int kk = 0; kk < 2; kk++)
        pf[qq][kk] = *(const short8*)&Ps[wid][(qq * 16 + frow) * 64 + (((kk * 4 + fk) ^ (frow & 7)) << 3)];
#pragma unroll
    for (int df = 0; df < 8; df++)
#pragma unroll
      for (int kk = 0; kk < 2; kk++) {
        short8 vf = *(const short8*)&Vb[swz64(df * 16 + frow, kk * 4 + fk)];
        acc_o[0][df] = __builtin_amdgcn_mfma_f32_16x16x32_bf16(vf, pf[0][kk], acc_o[0][df], 0, 0, 0);
        acc_o[1][df] = __builtin_amdgcn_mfma_f32_16x16x32_bf16(vf, pf[1][kk], acc_o[1][df], 0, 0, 0);
      }
    __syncthreads();  // drain + barrier: all reads done before next-iter stage overwrites
  }
#undef STAGE_KV

#pragma unroll
  for (int qq = 0; qq < 2; ++qq) {
    float inv = 1.0f / l_r[qq];
    long srow = (long)(b * S_ + q0 + wid * 32 + qq * 16 + frow);
    u16* orow = obuf + srow * D_ + h * HD_ + fk * 4;
#pragma unroll
    for (int df = 0; df < 8; df++) {
      uint2 ov;
      ov.x = pack2bf(acc_o[qq][df][0] * inv, acc_o[qq][df][1] * inv);
      ov.y = pack2bf(acc_o[qq][df][2] * inv, acc_o[qq][df][3] * inv);
      *(uint2*)(orow + df * 16) = ov;
    }
  }
}

// ---------------- launch ----------------
extern "C" void kernel_launch(void* const* d_in, const int* in_sizes, int n_in,
                              void* d_out, int out_size, void* d_ws, size_t ws_size,
                              hipStream_t stream) {
  const float* x = (const float*)d_in[0];
  const float* wq = (const float*)d_in[1];
  const float* wk = (const float*)d_in[2];
  const float* wv = (const float*)d_in[3];
  const float* wo = (const float*)d_in[4];
  const float* cosb = (const float*)d_in[5];
  const float* sinb = (const float*)d_in[6];
  const int* start_pos = (const int*)d_in[9];
  float* out = (float*)d_out;

  char* ws = (char*)d_ws;
  u16* xb = (u16*)ws;                                   // [8192][4096] bf16: 67108864 B
  u16* wqkvT = (u16*)(ws + 67108864L);                  // [6144][4096] bf16: 50331648 B
  u16* woT = (u16*)(ws + 117440512L);                   // [4096][4096] bf16: 33554432 B
  u16* qkvb = (u16*)(ws + 150994944L);                  // [8192][6144] bf16: 100663296 B
  u16* vtb = (u16*)(ws + 251658240L);                   // [4][8][128][2048] bf16: 16777216 B
  u16* obuf = xb;                                       // reuse xb after GEMM1

  // 1. cast x
  cast_f32_to_bf16<<<dim3(32768), dim3(256), 0, stream>>>(x, xb, (long)MTOT * D_);

  // 2. transpose-cast weights into B^T layout
  transpose_cast<<<dim3(128, 128), dim3(32, 8), 0, stream>>>(wq, wqkvT, D_, 4096);
  transpose_cast<<<dim3(32, 128), dim3(32, 8), 0, stream>>>(wk, wqkvT + (long)4096 * D_, D_, 1024);
  transpose_cast<<<dim3(32, 128), dim3(32, 8), 0, stream>>>(wv, wqkvT + (long)5120 * D_, D_, 1024);
  transpose_cast<<<dim3(128, 128), dim3(32, 8), 0, stream>>>(wo, woT, D_, 4096);

  // 3. QKV GEMM: [8192][6144] = xb * wqkvT^T  (256^2 8-phase)
  gemm256<0><<<dim3(NQKV / 256, MTOT / 256), dim3(512), 0, stream>>>(xb, wqkvT, qkvb, MTOT, NQKV, D_);

  // 4. RoPE in-place on K columns only (Q fused into attn)
  rope_k_kernel<<<dim3(16384), dim3(256), 0, stream>>>(qkvb, cosb, sinb, start_pos);

  // 5. V transpose
  build_vt<<<dim3(64, 4, 32), dim3(32, 8), 0, stream>>>(qkvb, vtb);

  // 6. attention: flat grid 16 x 128 = 2048
  attn_kernel<<<dim3(2048), dim3(256), 0, stream>>>(qkvb, vtb, obuf, cosb, sinb, start_pos);

  // 7. output GEMM: out f32 = obuf * woT^T  (256^2 8-phase)
  gemm256<1><<<dim3(D_ / 256, MTOT / 256), dim3(512), 0, stream>>>(obuf, woT, out, MTOT, D_, D_);
}

// Round 13
// 1022.995 us; speedup vs baseline: 1.0620x; 1.0173x over previous
//
#include <hip/hip_runtime.h>
#include <math.h>
#include <stdint.h>

typedef unsigned short u16;
typedef __attribute__((ext_vector_type(8))) short short8;
typedef __attribute__((ext_vector_type(4))) float f32x4;

#define B_   4
#define S_   2048
#define D_   4096
#define H_   32
#define KVH_ 8
#define HD_  128
#define NQKV 6144
#define MTOT 8192
#define ATT_SCALE 0.08838834764831845f
#define QSCL (ATT_SCALE * 1.4426950408889634f)  // fold scale*log2(e) into Q
#define DEFER_L2 11.541560327111707f            // 8*log2(e): P bounded by e^8

__device__ __forceinline__ float bf2f(u16 u) {
  unsigned x = ((unsigned)u) << 16;
  return __builtin_bit_cast(float, x);
}
__device__ __forceinline__ u16 f2bf(float f) {
  unsigned x = __builtin_bit_cast(unsigned, f);
  x += 0x7fffu + ((x >> 16) & 1u);
  return (u16)(x >> 16);
}
// branch-free RNE pack
__device__ __forceinline__ unsigned pack2bf(float a, float b) {
  return (unsigned)f2bf(a) | ((unsigned)f2bf(b) << 16);
}
// native 2^x (documented VOP1: v_exp_f32 D = 2^S0)
__device__ __forceinline__ float exp2_hw(float x) {
  float r;
  asm("v_exp_f32 %0, %1" : "=v"(r) : "v"(x));
  return r;
}

// async global->LDS, 16B per lane. LDS dest = wave-uniform base + lane*16.
typedef const __attribute__((address_space(1))) void* gas1p;
typedef __attribute__((address_space(3))) void* las3p;
__device__ __forceinline__ void gload16(const void* g, void* l) {
  __builtin_amdgcn_global_load_lds((gas1p)g, (las3p)l, 16, 0, 0);
}

// swizzled element index for LDS tiles with 64-element (128B) rows, chunk=8 elems
__device__ __forceinline__ int swz64(int row, int kc) {
  return row * 64 + ((kc ^ (row & 7)) << 3);
}
// 128-element (256B) rows, kc 0..15
__device__ __forceinline__ int swz128(int row, int kc) {
  return row * 128 + ((kc ^ (row & 7)) << 3);
}

// ---------------- cast x (f32 -> bf16) ----------------
__global__ void cast_f32_to_bf16(const float* __restrict__ in, u16* __restrict__ out, long n) {
  long i = ((long)blockIdx.x * 256 + threadIdx.x) * 4;
  if (i >= n) return;
  float4 v = *(const float4*)(in + i);
  ushort4 o;
  o.x = f2bf(v.x); o.y = f2bf(v.y); o.z = f2bf(v.z); o.w = f2bf(v.w);
  *(ushort4*)(out + i) = o;
}

// ---------------- transpose+cast weight: f32 [K][N] -> bf16 [N][K] ----------------
__global__ void transpose_cast(const float* __restrict__ in, u16* __restrict__ out, int K, int N) {
  __shared__ u16 tile[32][33];
  int n0 = blockIdx.x * 32, k0 = blockIdx.y * 32;
  int tx = threadIdx.x, ty = threadIdx.y;
  for (int i = ty; i < 32; i += 8)
    tile[i][tx] = f2bf(in[(long)(k0 + i) * N + n0 + tx]);
  __syncthreads();
  for (int i = ty; i < 32; i += 8)
    out[(long)(n0 + i) * K + k0 + tx] = tile[tx][i];
}

// ---------------- 256x256 8-phase GEMM: C = A[M][K] * BT[N][K]^T -----------------
template <int OUTF32>
__global__ __launch_bounds__(512, 2) void gemm256(const u16* __restrict__ A,
                                                  const u16* __restrict__ BT,
                                                  void* __restrict__ Cout,
                                                  int M, int N, int K) {
  __shared__ u16 Ls[2][2][2][128 * 64];
  int tid = threadIdx.x, lane = tid & 63, wid = tid >> 6;
  int wm = wid >> 2, wn = wid & 3;
  int m0 = blockIdx.y * 256, n0 = blockIdx.x * 256;
  int frow = lane & 15, fk = lane >> 4;

  f32x4 acc[8][4];
#pragma unroll
  for (int i = 0; i < 8; i++)
#pragma unroll
    for (int j = 0; j < 4; j++) acc[i][j] = (f32x4){0.f, 0.f, 0.f, 0.f};

  // stage source (pre-swizzled col: involution key = row-within-half & 7 = lane>>3)
  int srow = lane >> 3;
  int sc = ((lane & 7) ^ srow) * 8;
  const u16* a0 = A + (long)(m0 + (2 * wid + 0) * 8 + srow) * K + sc;
  const u16* a1 = A + (long)(m0 + (2 * wid + 1) * 8 + srow) * K + sc;
  const u16* b0 = BT + (long)(n0 + (2 * wid + 0) * 8 + srow) * K + sc;
  const u16* b1 = BT + (long)(n0 + (2 * wid + 1) * 8 + srow) * K + sc;
  long hstep = (long)128 * K;

#define STAGE_A(buf, half, t) do {                                              \
    gload16(a0 + (half) * hstep + (long)(t) * 64, &Ls[buf][0][half][(2 * wid + 0) * 512]); \
    gload16(a1 + (half) * hstep + (long)(t) * 64, &Ls[buf][0][half][(2 * wid + 1) * 512]); \
  } while (0)
#define STAGE_B(buf, half, t) do {                                              \
    gload16(b0 + (half) * hstep + (long)(t) * 64, &Ls[buf][1][half][(2 * wid + 0) * 512]); \
    gload16(b1 + (half) * hstep + (long)(t) * 64, &Ls[buf][1][half][(2 * wid + 1) * 512]); \
  } while (0)

  int nk = K / 64;
  // prologue: tile0 (buf0) all 4 halves, then tile1 B halves -> vmcnt(4)
  STAGE_A(0, 0, 0); STAGE_A(0, 1, 0); STAGE_B(0, 0, 0); STAGE_B(0, 1, 0);
  STAGE_B(1, 0, 1); STAGE_B(1, 1, 1);
  asm volatile("s_waitcnt vmcnt(4)" ::: "memory");
  __builtin_amdgcn_s_barrier();

#define PHASE(P, STAGE_STMT, VM_STMT)                                           \
  {                                                                             \
    short8 af[2][2];                                                            \
    _Pragma("unroll") for (int mm = 0; mm < 2; mm++)                            \
      _Pragma("unroll") for (int kk = 0; kk < 2; kk++)                          \
        af[mm][kk] = *(const short8*)&Ah[swz64((2 * (P) + mm) * 16 + frow, kk * 4 + fk)]; \
    STAGE_STMT;                                                                 \
    VM_STMT;                                                                    \
    __builtin_amdgcn_s_barrier();                                               \
    asm volatile("s_waitcnt lgkmcnt(0)" ::: "memory");                          \
    __builtin_amdgcn_sched_barrier(0);                                          \
    __builtin_amdgcn_s_setprio(1);                                              \
    _Pragma("unroll") for (int mm = 0; mm < 2; mm++)                            \
      _Pragma("unroll") for (int n = 0; n < 4; n++)                             \
        _Pragma("unroll") for (int kk = 0; kk < 2; kk++)                        \
          acc[2 * (P) + mm][n] = __builtin_amdgcn_mfma_f32_16x16x32_bf16(       \
              af[mm][kk], bfr[n][kk], acc[2 * (P) + mm][n], 0, 0, 0);           \
    __builtin_amdgcn_s_setprio(0);                                              \
    __builtin_amdgcn_s_barrier();                                               \
  }

  for (int t = 0; t < nk; ++t) {
    int pi = t & 1;
    const u16* Ah = &Ls[pi][0][wm][0];
    const u16* Bh = &Ls[pi][1][wn >> 1][0];
    int brow = (wn & 1) * 64;
    short8 bfr[4][2];
#pragma unroll
    for (int n = 0; n < 4; n++)
#pragma unroll
      for (int kk = 0; kk < 2; kk++)
        bfr[n][kk] = *(const short8*)&Bh[swz64(brow + n * 16 + frow, kk * 4 + fk)];

    PHASE(0, if (t + 1 < nk) STAGE_A(pi ^ 1, 0, t + 1), );
    PHASE(1, if (t + 1 < nk) STAGE_A(pi ^ 1, 1, t + 1), );
    PHASE(2, if (t + 2 < nk) STAGE_B(pi, 0, t + 2), );
    PHASE(3, if (t + 2 < nk) STAGE_B(pi, 1, t + 2),
          if (t + 2 < nk) { asm volatile("s_waitcnt vmcnt(4)" ::: "memory"); }
          else            { asm volatile("s_waitcnt vmcnt(0)" ::: "memory"); });
  }
#undef PHASE
#undef STAGE_A
#undef STAGE_B

  // epilogue: C/D layout col=lane&15 (from B), row=fk*4+reg (from A)
  int cc = lane & 15, cr = fk * 4;
#pragma unroll
  for (int i = 0; i < 8; i++)
#pragma unroll
    for (int j = 0; j < 4; j++)
#pragma unroll
      for (int r = 0; r < 4; r++) {
        int m = m0 + wm * 128 + i * 16 + cr + r;
        int n = n0 + wn * 64 + j * 16 + cc;
        if (OUTF32)
          ((float*)Cout)[(long)m * N + n] = acc[i][j][r];
        else
          ((u16*)Cout)[(long)m * N + n] = f2bf(acc[i][j][r]);
      }
}

// ---------------- RoPE in-place on qkv buffer: K columns only -------------------
__global__ void rope_k_kernel(u16* __restrict__ qkv, const float* __restrict__ cosb,
                              const float* __restrict__ sinb, const int* __restrict__ start_pos) {
  long tid = (long)blockIdx.x * 256 + threadIdx.x;
  const long total = (long)MTOT * 512;  // 512 K pairs per row
  if (tid >= total) return;
  int row = (int)(tid >> 9);
  int p = (int)(tid & 511);
  int col = D_ + p * 2;
  int i = p & 63;
  int s = row & (S_ - 1);
  int pos = s + *start_pos;
  float c = cosb[pos * 64 + i];
  float sn = sinb[pos * 64 + i];
  u16* ptr = qkv + (long)row * NQKV + col;
  unsigned v = *(unsigned*)ptr;
  float x0 = bf2f((u16)(v & 0xffff));
  float x1 = bf2f((u16)(v >> 16));
  float o0 = x0 * c - x1 * sn;
  float o1 = x0 * sn + x1 * c;
  *(unsigned*)ptr = pack2bf(o0, o1);
}

// ---------------- build VT[b][kvh][d=128][s=2048] from qkv V columns ----------------
__global__ void build_vt(const u16* __restrict__ qkv, u16* __restrict__ vt) {
  int bk = blockIdx.z;
  int b = bk >> 3, kvh = bk & 7;
  int s0 = blockIdx.x * 32, d0 = blockIdx.y * 32;
  __shared__ u16 tile[32][33];
  int tx = threadIdx.x, ty = threadIdx.y;
  const u16* src = qkv + (long)(b * S_) * NQKV + D_ + KVH_ * HD_ + kvh * HD_;
  for (int i = ty; i < 32; i += 8)
    tile[i][tx] = src[(long)(s0 + i) * NQKV + d0 + tx];
  __syncthreads();
  u16* dst = vt + ((long)(b * KVH_ + kvh) * HD_) * S_;
  for (int i = ty; i < 32; i += 8)
    dst[(long)(d0 + i) * S_ + s0 + tx] = tile[tx][i];
}

// ---------------- flash attention (non-causal, GQA), swapped-operand form -------
// 128 q/block (4 waves x 32 q). K/V LDS double-buffered, counted vmcnt(8).
// Q-RoPE fused at fragment load with scale*log2e folded in -> scores arrive in
// log2 domain; P = 2^(s-m) via native v_exp_f32 (sub+exp only). Per-lane partial
// l (cross-lane reduce deferred to epilogue). Defer-max rescale (THR=8, log2).
__global__ __launch_bounds__(256, 2) void attn_kernel(const u16* __restrict__ qkv,
                                                      const u16* __restrict__ vt,
                                                      u16* __restrict__ obuf,
                                                      const float* __restrict__ cosb,
                                                      const float* __restrict__ sinb,
                                                      const int* __restrict__ start_pos) {
  int nb = gridDim.x;
  int fid = (int)((blockIdx.x & 7) * (nb >> 3) + (blockIdx.x >> 3));
  int bx = fid & 15;
  int bh = fid >> 4;
  int b = bh >> 5, h = bh & 31;
  int kvh = h >> 2;
  int q0 = bx * 128;
  int tid = threadIdx.x, lane = tid & 63, wid = tid >> 6;

  __shared__ u16 Ks[2][64 * 128];
  __shared__ u16 VTs[2][128 * 64];
  __shared__ u16 Ps[4][32 * 64];

  int frow = lane & 15;
  int fk = lane >> 4;

  // Q fragments: fused RoPE + QSCL fold. 8 elems at d = kd*32 + fk*8 = 4 aligned pairs
  short8 qf[2][4];
#pragma unroll
  for (int qq = 0; qq < 2; ++qq) {
    int s = q0 + wid * 32 + qq * 16 + frow;
    int pos = s + *start_pos;
    const float* cb = cosb + pos * 64;
    const float* sb = sinb + pos * 64;
    const u16* qbase = qkv + (long)(b * S_ + s) * NQKV + h * HD_;
#pragma unroll
    for (int kd = 0; kd < 4; ++kd) {
      short8 v = *(const short8*)(qbase + kd * 32 + fk * 8);
      union { short8 s8; unsigned u[4]; } w;
#pragma unroll
      for (int j = 0; j < 4; ++j) {
        int i = kd * 16 + fk * 4 + j;
        float c = cb[i], sn = sb[i];
        float x0 = bf2f((u16)v[2 * j]), x1 = bf2f((u16)v[2 * j + 1]);
        w.u[j] = pack2bf((x0 * c - x1 * sn) * QSCL, (x0 * sn + x1 * c) * QSCL);
      }
      qf[qq][kd] = w.s8;
    }
  }

  f32x4 acc_o[2][8];
#pragma unroll
  for (int qq = 0; qq < 2; qq++)
#pragma unroll
    for (int i = 0; i < 8; i++) acc_o[qq][i] = (f32x4){0.f, 0.f, 0.f, 0.f};
  float m_r[2] = {-1e30f, -1e30f};
  float l_r[2] = {0.f, 0.f};   // per-lane partial (this fk group); reduced at end

  const u16* kgl[4];
  const u16* vgl[4];
#pragma unroll
  for (int j = 0; j < 4; j++) {
    int gk = j * 4 + wid;
    int rk = gk * 4 + (lane >> 4);
    int ck = (lane & 15) ^ (rk & 7);
    kgl[j] = qkv + (long)(b * S_ + rk) * NQKV + D_ + kvh * HD_ + ck * 8;
    int gv = j * 4 + wid;
    int rv = gv * 8 + (lane >> 3);
    int cv = (lane & 7) ^ (rv & 7);
    vgl[j] = vt + ((long)(b * KVH_ + kvh) * HD_ + rv) * S_ + cv * 8;
  }

#define STAGE_KV(buf, t) do {                                                   \
    _Pragma("unroll") for (int j = 0; j < 4; j++) {                             \
      int g = j * 4 + wid;                                                      \
      gload16(kgl[j] + (long)((t) * 64) * NQKV, &Ks[buf][g * 512]);             \
      gload16(vgl[j] + (t) * 64, &VTs[buf][g * 512]);                           \
    }                                                                           \
  } while (0)

  const int ntiles = S_ / 64;
  STAGE_KV(0, 0);

  for (int t = 0; t < ntiles; ++t) {
    if (t + 1 < ntiles) {
      STAGE_KV((t + 1) & 1, t + 1);
      asm volatile("s_waitcnt vmcnt(8)" ::: "memory");  // tile t's 8 done; t+1 in flight
    } else {
      asm volatile("s_waitcnt vmcnt(0)" ::: "memory");
    }
    __builtin_amdgcn_s_barrier();   // raw: do NOT drain the in-flight prefetch
    __builtin_amdgcn_sched_barrier(0);
    const u16* Kb = &Ks[t & 1][0];
    const u16* Vb = &VTs[t & 1][0];

    // QK^T swapped (scores pre-scaled to log2 domain via QSCL-folded Q)
    f32x4 sc[4][2];
#pragma unroll
    for (int f = 0; f < 4; f++)
#pragma unroll
      for (int qq = 0; qq < 2; qq++) sc[f][qq] = (f32x4){0.f, 0.f, 0.f, 0.f};
#pragma unroll
    for (int f = 0; f < 4; f++)
#pragma unroll
      for (int kd = 0; kd < 4; kd++) {
        short8 kf = *(const short8*)&Kb[swz128(f * 16 + frow, kd * 4 + fk)];
        sc[f][0] = __builtin_amdgcn_mfma_f32_16x16x32_bf16(kf, qf[0][kd], sc[f][0], 0, 0, 0);
        sc[f][1] = __builtin_amdgcn_mfma_f32_16x16x32_bf16(kf, qf[1][kd], sc[f][1], 0, 0, 0);
      }

    // tile max per qq (max3-friendly grouping) + 2 shfl
    float mx[2];
#pragma unroll
    for (int qq = 0; qq < 2; ++qq) {
      float mf[4];
#pragma unroll
      for (int f = 0; f < 4; f++)
        mf[f] = fmaxf(fmaxf(fmaxf(sc[f][qq][0], sc[f][qq][1]), sc[f][qq][2]), sc[f][qq][3]);
      float m = fmaxf(fmaxf(fmaxf(mf[0], mf[1]), mf[2]), mf[3]);
      m = fmaxf(m, __shfl_xor(m, 16, 64));
      m = fmaxf(m, __shfl_xor(m, 32, 64));
      mx[qq] = m;
    }
    // defer-max: rescale only if some row's max grew past THR (log2 units)
    if (!__all((mx[0] <= m_r[0] + DEFER_L2) && (mx[1] <= m_r[1] + DEFER_L2))) {
#pragma unroll
      for (int qq = 0; qq < 2; ++qq) {
        float mnew = fmaxf(m_r[qq], mx[qq]);
        float scl = exp2_hw(m_r[qq] - mnew);
        l_r[qq] *= scl;
        m_r[qq] = mnew;
#pragma unroll
        for (int df = 0; df < 8; df++) acc_o[qq][df] *= scl;
      }
    }

    // P = 2^(s - m), bf16-pack to LDS; per-lane partial row-sum into l
#pragma unroll
    for (int qq = 0; qq < 2; ++qq) {
      float nm = m_r[qq];
      float rs = 0.f;
      int prow = qq * 16 + frow;
      int pbase = prow * 64 + (fk & 1) * 4;
      int q7 = frow & 7;
#pragma unroll
      for (int f = 0; f < 4; f++) {
        float p0 = exp2_hw(sc[f][qq][0] - nm);
        float p1 = exp2_hw(sc[f][qq][1] - nm);
        float p2 = exp2_hw(sc[f][qq][2] - nm);
        float p3 = exp2_hw(sc[f][qq][3] - nm);
        rs += (p0 + p1) + (p2 + p3);
        int chunk = (f * 2 + (fk >> 1)) ^ q7;
        uint2 wv2; wv2.x = pack2bf(p0, p1); wv2.y = pack2bf(p2, p3);
        *(uint2*)&Ps[wid][pbase + (chunk << 3)] = wv2;
      }
      l_r[qq] += rs;   // partial; cross-fk reduce deferred to epilogue
    }

    asm volatile("s_waitcnt lgkmcnt(0)" ::: "memory");
    __builtin_amdgcn_sched_barrier(0);

    // PV swapped: O^T += VT * P^T
    short8 pf[2][2];
#pragma unroll
    for (int qq = 0; qq < 2; qq++)
#pragma unroll
      for (int kk = 0; kk < 2; kk++)
        pf[qq][kk] = *(const short8*)&Ps[wid][(qq * 16 + frow) * 64 + (((kk * 4 + fk) ^ (frow & 7)) << 3)];
#pragma unroll
    for (int df = 0; df < 8; df++)
#pragma unroll
      for (int kk = 0; kk < 2; kk++) {
        short8 vf = *(const short8*)&Vb[swz64(df * 16 + frow, kk * 4 + fk)];
        acc_o[0][df] = __builtin_amdgcn_mfma_f32_16x16x32_bf16(vf, pf[0][kk], acc_o[0][df], 0, 0, 0);
        acc_o[1][df] = __builtin_amdgcn_mfma_f32_16x16x32_bf16(vf, pf[1][kk], acc_o[1][df], 0, 0, 0);
      }
    __syncthreads();  // drain + barrier: all reads done before next-iter stage overwrites
  }
#undef STAGE_KV

#pragma unroll
  for (int qq = 0; qq < 2; ++qq) {
    float lv = l_r[qq];
    lv += __shfl_xor(lv, 16, 64);
    lv += __shfl_xor(lv, 32, 64);
    float inv = 1.0f / lv;
    long srow = (long)(b * S_ + q0 + wid * 32 + qq * 16 + frow);
    u16* orow = obuf + srow * D_ + h * HD_ + fk * 4;
#pragma unroll
    for (int df = 0; df < 8; df++) {
      uint2 ov;
      ov.x = pack2bf(acc_o[qq][df][0] * inv, acc_o[qq][df][1] * inv);
      ov.y = pack2bf(acc_o[qq][df][2] * inv, acc_o[qq][df][3] * inv);
      *(uint2*)(orow + df * 16) = ov;
    }
  }
}

// ---------------- launch ----------------
extern "C" void kernel_launch(void* const* d_in, const int* in_sizes, int n_in,
                              void* d_out, int out_size, void* d_ws, size_t ws_size,
                              hipStream_t stream) {
  const float* x = (const float*)d_in[0];
  const float* wq = (const float*)d_in[1];
  const float* wk = (const float*)d_in[2];
  const float* wv = (const float*)d_in[3];
  const float* wo = (const float*)d_in[4];
  const float* cosb = (const float*)d_in[5];
  const float* sinb = (const float*)d_in[6];
  const int* start_pos = (const int*)d_in[9];
  float* out = (float*)d_out;

  char* ws = (char*)d_ws;
  u16* xb = (u16*)ws;                                   // [8192][4096] bf16: 67108864 B
  u16* wqkvT = (u16*)(ws + 67108864L);                  // [6144][4096] bf16: 50331648 B
  u16* woT = (u16*)(ws + 117440512L);                   // [4096][4096] bf16: 33554432 B
  u16* qkvb = (u16*)(ws + 150994944L);                  // [8192][6144] bf16: 100663296 B
  u16* vtb = (u16*)(ws + 251658240L);                   // [4][8][128][2048] bf16: 16777216 B
  u16* obuf = xb;                                       // reuse xb after GEMM1

  // 1. cast x
  cast_f32_to_bf16<<<dim3(32768), dim3(256), 0, stream>>>(x, xb, (long)MTOT * D_);

  // 2. transpose-cast weights into B^T layout
  transpose_cast<<<dim3(128, 128), dim3(32, 8), 0, stream>>>(wq, wqkvT, D_, 4096);
  transpose_cast<<<dim3(32, 128), dim3(32, 8), 0, stream>>>(wk, wqkvT + (long)4096 * D_, D_, 1024);
  transpose_cast<<<dim3(32, 128), dim3(32, 8), 0, stream>>>(wv, wqkvT + (long)5120 * D_, D_, 1024);
  transpose_cast<<<dim3(128, 128), dim3(32, 8), 0, stream>>>(wo, woT, D_, 4096);

  // 3. QKV GEMM: [8192][6144] = xb * wqkvT^T  (256^2 8-phase)
  gemm256<0><<<dim3(NQKV / 256, MTOT / 256), dim3(512), 0, stream>>>(xb, wqkvT, qkvb, MTOT, NQKV, D_);

  // 4. RoPE in-place on K columns only (Q fused into attn)
  rope_k_kernel<<<dim3(16384), dim3(256), 0, stream>>>(qkvb, cosb, sinb, start_pos);

  // 5. V transpose
  build_vt<<<dim3(64, 4, 32), dim3(32, 8), 0, stream>>>(qkvb, vtb);

  // 6. attention: flat grid 16 x 128 = 2048
  attn_kernel<<<dim3(2048), dim3(256), 0, stream>>>(qkvb, vtb, obuf, cosb, sinb, start_pos);

  // 7. output GEMM: out f32 = obuf * woT^T  (256^2 8-phase)
  gemm256<1><<<dim3(D_ / 256, MTOT / 256), dim3(512), 0, stream>>>(obuf, woT, out, MTOT, D_, D_);
}